// Round 17
// baseline (1386.694 us; speedup 1.0000x reference)
//
#include <hip/hip_runtime.h>
#include <math.h>

#define NREV 16384
#define NUSER 65536
#define NPROD 65536
#define KNBR 16
#define LDK 72   // padded LDS stride (bf16 elems): rows 16B-aligned, cheap bank phases

typedef __attribute__((ext_vector_type(8))) short short8;   // 8 bf16 (4 VGPRs) — MFMA A/B frag
typedef __attribute__((ext_vector_type(4))) float f32x4;    // MFMA C/D frag
typedef unsigned short u16;

__device__ __forceinline__ u16 f2bf(float f){
  union { float f; unsigned u; } x; x.f = f;
  unsigned r = x.u + 0x7fffu + ((x.u >> 16) & 1u);  // RNE
  return (u16)(r >> 16);
}
__device__ __forceinline__ float bf2f(u16 u){
  union { unsigned u; float f; } x; x.u = ((unsigned)u) << 16;
  return x.f;
}
// fast transcendentals: v_exp_f32 (2^x) + v_rcp_f32 direct. Saturation at +-inf is exact.
__device__ __forceinline__ float fexp2(float x){ return __builtin_amdgcn_exp2f(x); }
__device__ __forceinline__ float frcp(float x){ return __builtin_amdgcn_rcpf(x); }
#define LOG2E 1.4426950408889634f
__device__ __forceinline__ float sigf(float x){ return frcp(1.f + fexp2(-LOG2E*x)); }
__device__ __forceinline__ float tanh_fast(float x){ return 1.f - 2.f*frcp(1.f + fexp2(2.f*LOG2E*x)); }
__device__ __forceinline__ float gelu_fast(float x){
  float u = 0.7978845608f*x*(1.f + 0.044715f*x*x);
  return 0.5f*x*(1.f + tanh_fast(u));
}

// ---------------- f32 -> bf16 bulk convert (x_review only) ----------------
__global__ void cvt_kernel(const float* __restrict__ src, u16* __restrict__ dst, int n4){
  int i = blockIdx.x*256 + threadIdx.x;
  if(i < n4){
    float4 v = reinterpret_cast<const float4*>(src)[i];
    ushort4 o; o.x=f2bf(v.x); o.y=f2bf(v.y); o.z=f2bf(v.z); o.w=f2bf(v.w);
    reinterpret_cast<ushort4*>(dst)[i] = o;
  }
}

// ---------------- pack LSTM weights ----------------
// Bpp[n][k]: n = 4*j + gate, k = [Wih | Whh] (xw kernel uses k<256 rows).
// Bfp: Whh half ALSO packed fragment-major for direct global->reg MFMA loads:
//   idx = (((n16*4 + kt)*2 + kk)*64 + lane)*8 + e, where lane = rrow + 16*lhi,
//   k = kt*64 + kk*32 + lhi*8 + e, n = n16*16 + rrow.
__global__ void pack_lstm_kernel(const float* __restrict__ Wihp, const float* __restrict__ Whhp,
                                 const float* __restrict__ bihp, const float* __restrict__ bhhp,
                                 u16* __restrict__ Bpp, u16* __restrict__ Bfp, float* __restrict__ bpp){
  int n = blockIdx.x;              // 0..1023
  int g = n & 3, j = n >> 2;       // gate order i,f,g,o
  int m = g*256 + j;               // row in original (4F,F) weight
  int k = threadIdx.x;             // 0..255
  Bpp[(size_t)n*512 + k]       = f2bf(Wihp[(size_t)m*256 + k]);
  u16 whh = f2bf(Whhp[(size_t)m*256 + k]);
  Bpp[(size_t)n*512 + 256 + k] = whh;
  int n16 = n >> 4, rrow = n & 15;
  int kt = k >> 6, kk = (k >> 5) & 1, lhi = (k >> 3) & 3, e = k & 7;
  int lane = rrow + lhi*16;
  Bfp[((((size_t)n16*4 + kt)*2 + kk)*64 + lane)*8 + e] = whh;
  if(k == 0) bpp[n] = bihp[m] + bhhp[m];
}

// ---------------- pack SAGE weights: Bs[n][k], k = [Wself | Wneigh] ----------------
__global__ void pack_sage_kernel(const float* __restrict__ Wselfp, const float* __restrict__ Wneighp,
                                 u16* __restrict__ Bsp){
  int n = blockIdx.x;              // 0..255
  int k = threadIdx.x;
  Bsp[(size_t)n*512 + k]       = f2bf(Wselfp[(size_t)n*256 + k]);
  Bsp[(size_t)n*512 + 256 + k] = f2bf(Wneighp[(size_t)n*256 + k]);
}

// ---------------- xW precompute v3 (r16 proven): LDS GEMM + coalesced LDS epilogue ----------------
__global__ __launch_bounds__(256, 4) void xw_kernel(
    const float* __restrict__ x, const u16* __restrict__ Bp,
    const float* __restrict__ bp, u16* __restrict__ xwout)
{
  union SMX {
    struct { u16 A[128*LDK]; u16 B[128*LDK]; } st;  // 36.9 KB staging
    u16 O[128*136];                                  // 34.8 KB output tile (pad 136)
  };
  __shared__ SMX sm;
  int tid = threadIdx.x;
  int p = blockIdx.x;
  int xcd = p & 7, g = p >> 3;
  int nt = g & 7;
  int rt = (g >> 3) * 8 + xcd;             // 0..511
  f32x4 acc[4][4];
  #pragma unroll
  for(int i=0;i<4;++i)
    #pragma unroll
    for(int j=0;j<4;++j) acc[i][j] = (f32x4){0.f,0.f,0.f,0.f};
  int lane = tid & 63, w = tid >> 6, wr = w >> 1, wc = w & 1;
  int ci = tid & 7, r0 = tid >> 3;
  int rrow = lane & 15, lhi = lane >> 4, kb = lhi * 8;

  for(int kt=0; kt<4; ++kt){
    __syncthreads();
    #pragma unroll
    for(int pp=0; pp<4; ++pp){
      int row = pp*32 + r0;
      const float* srcA = x + (size_t)(rt*128 + row)*256 + kt*64 + ci*8;
      float4 a0 = *(const float4*)srcA;
      float4 a1 = *(const float4*)(srcA + 4);
      short8 s;
      s[0]=f2bf(a0.x); s[1]=f2bf(a0.y); s[2]=f2bf(a0.z); s[3]=f2bf(a0.w);
      s[4]=f2bf(a1.x); s[5]=f2bf(a1.y); s[6]=f2bf(a1.z); s[7]=f2bf(a1.w);
      *(short8*)&sm.st.A[row*LDK + ci*8] = s;
      *(short8*)&sm.st.B[row*LDK + ci*8] =
        *(const short8*)(Bp + (size_t)(nt*128 + row)*512 + kt*64 + ci*8);
    }
    __syncthreads();
    #pragma unroll
    for(int kk=0; kk<2; ++kk){
      short8 af[4], bfv[4];
      #pragma unroll
      for(int ni=0;ni<4;++ni) af[ni]  = *(const short8*)&sm.st.B[(wc*64+ni*16+rrow)*LDK + kk*32 + kb];
      #pragma unroll
      for(int mi=0;mi<4;++mi) bfv[mi] = *(const short8*)&sm.st.A[(wr*64+mi*16+rrow)*LDK + kk*32 + kb];
      #pragma unroll
      for(int ni=0;ni<4;++ni)
        #pragma unroll
        for(int mi=0;mi<4;++mi)
          acc[ni][mi] = __builtin_amdgcn_mfma_f32_16x16x32_bf16(af[ni], bfv[mi], acc[ni][mi], 0, 0, 0);
    }
  }
  __syncthreads();   // all MFMA LDS reads done before aliasing
  #pragma unroll
  for(int mi=0;mi<4;++mi){
    int rl = wr*64 + mi*16 + rrow;
    #pragma unroll
    for(int ni=0;ni<4;++ni){
      int nl = wc*64 + ni*16 + lhi*4;
      float4 bv = *(const float4*)&bp[nt*128 + nl];
      ushort4 o;
      o.x = f2bf(acc[ni][mi][0] + bv.x);
      o.y = f2bf(acc[ni][mi][1] + bv.y);
      o.z = f2bf(acc[ni][mi][2] + bv.z);
      o.w = f2bf(acc[ni][mi][3] + bv.w);
      *(ushort4*)&sm.O[rl*136 + nl] = o;
    }
  }
  __syncthreads();
  #pragma unroll
  for(int it=0; it<8; ++it){
    int rl = it*16 + (tid >> 4);
    int ch = tid & 15;
    *(short8*)(xwout + (size_t)(rt*128 + rl)*1024 + nt*128 + ch*8) =
      *(const short8*)&sm.O[rl*136 + ch*8];
  }
}

// ---------------- LSTM step v13: B-fragments direct from L2 (fragment-packed), sA-only LDS ----------------
// Tile 128r x 128n(packed), 256 thr, (256,3). LDS = 18.4 KB -> runtime occupancy 4 blocks/CU.
// 1D grid 1024, XCD-swizzled (8 nt-siblings of one rt on the SAME XCD -> hin L2 reuse).
__global__ __launch_bounds__(256, 3) void lstm_step13_kernel(
    const u16* __restrict__ xw, const int* __restrict__ nbr, int t,
    const u16* __restrict__ Bf,   // Whh fragment-packed (1 MB, L2-resident)
    const u16* __restrict__ hin, u16* __restrict__ hout, float* __restrict__ cT)
{
  __shared__ u16 sA[128*LDK];     // 18.4 KB
  int tid = threadIdx.x;
  int p = blockIdx.x;
  int xcd = p & 7, g = p >> 3;
  int nt = g & 7;
  int rt = (g >> 3) * 8 + xcd;             // 0..127
  int lane = tid & 63, w = tid >> 6, wr = w >> 1, wc = w & 1;
  int ci = tid & 7, r0 = tid >> 3;
  int rrow = lane & 15, lhi = lane >> 4, kb = lhi * 8;

  // gather prefetch: 16 x 8B loads in flight across the whole GEMM
  int node[4];
  #pragma unroll
  for(int mi=0;mi<4;++mi)
    node[mi] = nbr[(size_t)(rt*128 + wr*64 + mi*16 + rrow)*KNBR + t];
  ushort4 xv[4][4];
  #pragma unroll
  for(int mi=0;mi<4;++mi)
    #pragma unroll
    for(int ni=0;ni<4;++ni){
      int n0 = nt*128 + wc*64 + ni*16 + lhi*4;
      xv[mi][ni] = *(const ushort4*)(xw + (size_t)node[mi]*1024 + n0);
    }

  f32x4 acc[4][4];   // [ni][mi]
  #pragma unroll
  for(int i=0;i<4;++i)
    #pragma unroll
    for(int j=0;j<4;++j) acc[i][j] = (f32x4){0.f,0.f,0.f,0.f};

  if(t > 0){
    for(int kt=0; kt<4; ++kt){
      __syncthreads();
      #pragma unroll
      for(int pp=0; pp<4; ++pp){
        int row = pp*32 + r0;
        *(short8*)&sA[row*LDK + ci*8] =
          *(const short8*)(hin + (size_t)(rt*128 + row)*256 + kt*64 + ci*8);
      }
      __syncthreads();
      #pragma unroll
      for(int kk=0; kk<2; ++kk){
        short8 af[4], bfv[4];
        // B fragments: wave-coalesced 1KB loads from L2-resident fragment-packed Whh
        #pragma unroll
        for(int ni=0;ni<4;++ni){
          int n16 = nt*8 + wc*4 + ni;
          af[ni] = *(const short8*)(Bf + ((((size_t)n16*4 + kt)*2 + kk)*64 + lane)*8);
        }
        #pragma unroll
        for(int mi=0;mi<4;++mi) bfv[mi] = *(const short8*)&sA[(wr*64+mi*16+rrow)*LDK + kk*32 + kb];
        #pragma unroll
        for(int ni=0;ni<4;++ni)
          #pragma unroll
          for(int mi=0;mi<4;++mi)
            acc[ni][mi] = __builtin_amdgcn_mfma_f32_16x16x32_bf16(af[ni], bfv[mi], acc[ni][mi], 0, 0, 0);
      }
    }
  }

  // c loads issued after GEMM, before the transcendental chain
  float cv[4][4];
  #pragma unroll
  for(int mi=0;mi<4;++mi)
    #pragma unroll
    for(int ni=0;ni<4;++ni){
      cv[mi][ni] = 0.f;
      if(t > 0){
        int j = nt*32 + wc*16 + ni*4 + lhi;
        cv[mi][ni] = cT[(size_t)j*NREV + rt*128 + wr*64 + mi*16 + rrow];
      }
    }

  // fused cell update: acc elem q <-> packed n = 4*j + gate q (i,f,g,o)
  #pragma unroll
  for(int mi=0;mi<4;++mi){
    int rg = rt*128 + wr*64 + mi*16 + rrow;
    #pragma unroll
    for(int ni=0;ni<4;++ni){
      int j = nt*32 + wc*16 + ni*4 + lhi;
      float ig = bf2f(xv[mi][ni].x) + acc[ni][mi][0];
      float fg = bf2f(xv[mi][ni].y) + acc[ni][mi][1];
      float gg = bf2f(xv[mi][ni].z) + acc[ni][mi][2];
      float og = bf2f(xv[mi][ni].w) + acc[ni][mi][3];
      float cn = sigf(fg)*cv[mi][ni] + sigf(ig)*tanh_fast(gg);
      cT[(size_t)j*NREV + rg] = cn;
      hout[(size_t)rg*256 + j] = f2bf(sigf(og)*tanh_fast(cn));
    }
  }
}

// ---------------- generic GEMM + bias + GELU: MODE 0 = write f32, 1 = add f32, 2 = write bf16 ----------------
template<int MODE>
__global__ __launch_bounds__(256) void gemm_act_kernel(
    const u16* __restrict__ A0, const u16* __restrict__ A1,
    const u16* __restrict__ Bp, const float* __restrict__ bias,
    float* __restrict__ outF, u16* __restrict__ outH)
{
  constexpr int KT   = (MODE == 2) ? 4 : 8;
  constexpr int KTOT = KT * 64;
  __shared__ u16 sA[128*LDK];
  __shared__ u16 sB[128*LDK];
  int tid = threadIdx.x;
  int rt = blockIdx.x, nt = blockIdx.y;
  f32x4 acc[4][4];
  #pragma unroll
  for(int i=0;i<4;++i)
    #pragma unroll
    for(int j=0;j<4;++j) acc[i][j] = (f32x4){0.f,0.f,0.f,0.f};
  int lane = tid & 63, w = tid >> 6, wr = w >> 1, wc = w & 1;
  int ci = tid & 7, r0 = tid >> 3;
  int rrow = lane & 15, kb = (lane >> 4) * 8;

  for(int kt=0; kt<KT; ++kt){
    __syncthreads();
    #pragma unroll
    for(int pp=0; pp<4; ++pp){
      int row = pp*32 + r0;
      const u16* srcA = (kt < 4)
        ? (A0 + ((size_t)(rt*128 + row))*256 + kt*64)
        : (A1 + ((size_t)(rt*128 + row))*256 + (kt-4)*64);
      *(short8*)&sA[row*LDK + ci*8] = *(const short8*)(srcA + ci*8);
      const u16* srcB = Bp + ((size_t)(nt*128 + row))*KTOT + kt*64;
      *(short8*)&sB[row*LDK + ci*8] = *(const short8*)(srcB + ci*8);
    }
    __syncthreads();
    #pragma unroll
    for(int kk=0; kk<2; ++kk){
      short8 af[4], bfv[4];
      #pragma unroll
      for(int mi=0;mi<4;++mi) af[mi] = *(const short8*)&sA[(wr*64+mi*16+rrow)*LDK + kk*32 + kb];
      #pragma unroll
      for(int ni=0;ni<4;++ni) bfv[ni] = *(const short8*)&sB[(wc*64+ni*16+rrow)*LDK + kk*32 + kb];
      #pragma unroll
      for(int mi=0;mi<4;++mi)
        #pragma unroll
        for(int ni=0;ni<4;++ni)
          acc[mi][ni] = __builtin_amdgcn_mfma_f32_16x16x32_bf16(af[mi], bfv[ni], acc[mi][ni], 0, 0, 0);
    }
  }
  #pragma unroll
  for(int mi=0;mi<4;++mi)
    #pragma unroll
    for(int ni=0;ni<4;++ni){
      int col  = nt*128 + wc*64 + ni*16 + rrow;
      int rowb = rt*128 + wr*64 + mi*16 + (lane>>4)*4;
      float bv = bias[col];
      #pragma unroll
      for(int q=0;q<4;++q){
        float x = acc[mi][ni][q] + bv;
        float gl = gelu_fast(x);
        size_t idx = (size_t)(rowb+q)*256 + col;
        if(MODE == 0)      outF[idx] = gl;
        else if(MODE == 1) outF[idx] += gl;
        else               outH[idx] = f2bf(gl);
      }
    }
}

// ---------------- LayerNorm rowwise (256 feats), write bf16 ----------------
__global__ void ln_kernel(const float* __restrict__ hs, const float* __restrict__ g,
                          const float* __restrict__ b, u16* __restrict__ hlnp){
  int w = threadIdx.x >> 6, lane = threadIdx.x & 63;
  int r = blockIdx.x*4 + w;
  const float* row = hs + (size_t)r*256;
  float4 v = *(const float4*)(row + lane*4);
  float s  = v.x+v.y+v.z+v.w;
  float ss = v.x*v.x + v.y*v.y + v.z*v.z + v.w*v.w;
  #pragma unroll
  for(int d=1; d<64; d<<=1){ s += __shfl_xor(s, d, 64); ss += __shfl_xor(ss, d, 64); }
  float mu  = s  * (1.f/256.f);
  float var = ss * (1.f/256.f) - mu*mu;
  float rs  = rsqrtf(var + 1e-5f);
  float4 gv = *(const float4*)(g + lane*4);
  float4 bv = *(const float4*)(b + lane*4);
  ushort4 o;
  o.x = f2bf((v.x-mu)*rs*gv.x + bv.x);
  o.y = f2bf((v.y-mu)*rs*gv.y + bv.y);
  o.z = f2bf((v.z-mu)*rs*gv.z + bv.z);
  o.w = f2bf((v.w-mu)*rs*gv.w + bv.w);
  *(ushort4*)(hlnp + (size_t)r*256 + lane*4) = o;
}

// ---------------- column stats for BatchNorm ----------------
__global__ void colstats_kernel(const u16* __restrict__ hlnp, float* __restrict__ cs, float* __restrict__ cq){
  int cix = threadIdx.x;
  size_t rb = (size_t)blockIdx.x * 128;
  float s=0.f, q=0.f;
  for(int rr=0; rr<128; ++rr){
    float v = bf2f(hlnp[(rb+rr)*256 + cix]);
    s += v; q += v*v;
  }
  atomicAdd(&cs[cix], s);
  atomicAdd(&cq[cix], q);
}

// ---------------- BN stats -> scale/shift ----------------
__global__ void bnstat_kernel(const float* __restrict__ cs, const float* __restrict__ cq,
                              const float* __restrict__ bng, const float* __restrict__ bnb,
                              float* __restrict__ bns, float* __restrict__ bnt){
  int cix = threadIdx.x;
  float bm = cs[cix] * (1.f/16384.f);
  float bv = cq[cix] * (1.f/16384.f) - bm*bm;
  float s  = bng[cix] * rsqrtf(bv + 1e-5f);
  bns[cix] = s;
  bnt[cix] = bnb[cix] - bm*s;
}

// ---------------- fold BN into W1/b1 (parallel: one block per output row) ----------------
__global__ void w1fold_kernel(const float* __restrict__ W1p, const float* __restrict__ b1p,
                              const float* __restrict__ bns, const float* __restrict__ bnt,
                              u16* __restrict__ W1fp, float* __restrict__ b1fp){
  __shared__ float red[4];
  int n = blockIdx.x, k = threadIdx.x;
  int lane = k & 63, w = k >> 6;
  float wv = W1p[(size_t)n*256 + k];
  W1fp[(size_t)n*256 + k] = f2bf(wv * bns[k]);
  float p = wv * bnt[k];
  #pragma unroll
  for(int d=1; d<64; d<<=1) p += __shfl_xor(p, d, 64);
  if(lane == 0) red[w] = p;
  __syncthreads();
  if(k == 0) b1fp[n] = b1p[n] + red[0] + red[1] + red[2] + red[3];
}

// ---------------- head ----------------
__global__ void head_kernel(const u16* __restrict__ z, const float* __restrict__ W2p,
                            const float* __restrict__ b2p, float* __restrict__ outp){
  int w = threadIdx.x >> 6, lane = threadIdx.x & 63;
  int r = blockIdx.x*4 + w;
  const u16* zr = z + (size_t)r*256;
  ushort4 v = *(const ushort4*)(zr + lane*4);
  float z0=bf2f(v.x), z1v=bf2f(v.y), z2=bf2f(v.z), z3=bf2f(v.w);
  float4 wa = *(const float4*)(W2p + lane*4);
  float4 wb = *(const float4*)(W2p + 256 + lane*4);
  float p0 = z0*wa.x + z1v*wa.y + z2*wa.z + z3*wa.w;
  float p1 = z0*wb.x + z1v*wb.y + z2*wb.z + z3*wb.w;
  #pragma unroll
  for(int d=1; d<64; d<<=1){ p0 += __shfl_xor(p0,d,64); p1 += __shfl_xor(p1,d,64); }
  if(lane == 0){
    outp[(size_t)r*2]   = p0 + b2p[0];
    outp[(size_t)r*2+1] = p1 + b2p[1];
  }
}

extern "C" void kernel_launch(void* const* d_in, const int* in_sizes, int n_in,
                              void* d_out, int out_size, void* d_ws, size_t ws_size,
                              hipStream_t stream){
  (void)in_sizes; (void)n_in; (void)out_size;
  const float* x_user    = (const float*)d_in[0];
  const float* x_product = (const float*)d_in[1];
  const float* x_review  = (const float*)d_in[2];
  const int*   nbr_user  = (const int*)d_in[3];
  const int*   nbr_prod  = (const int*)d_in[4];
  const float* Wih[2]    = {(const float*)d_in[5],  (const float*)d_in[12]};
  const float* Whh[2]    = {(const float*)d_in[6],  (const float*)d_in[13]};
  const float* bih[2]    = {(const float*)d_in[7],  (const float*)d_in[14]};
  const float* bhh[2]    = {(const float*)d_in[8],  (const float*)d_in[15]};
  const float* Wself[2]  = {(const float*)d_in[9],  (const float*)d_in[16]};
  const float* Wneigh[2] = {(const float*)d_in[10], (const float*)d_in[17]};
  const float* bconv[2]  = {(const float*)d_in[11], (const float*)d_in[18]};
  const float* ln_g=(const float*)d_in[19], *ln_b=(const float*)d_in[20];
  const float* bn_g=(const float*)d_in[21], *bn_b=(const float*)d_in[22];
  const float* W1=(const float*)d_in[23], *b1=(const float*)d_in[24];
  const float* W2=(const float*)d_in[25], *b2=(const float*)d_in[26];
  float* out = (float*)d_out;

  char* base = (char*)d_ws;
  size_t off = 0;
  auto alloc = [&](size_t bytes)->char* { char* r = base + off; off += (bytes + 255) & ~(size_t)255; return r; };
  u16*   xr   = (u16*)  alloc((size_t)NREV*256*2);
  float* hsum = (float*)alloc((size_t)NREV*256*4);
  u16*   Bp[2]; Bp[0]=(u16*)alloc(1024*512*2); Bp[1]=(u16*)alloc(1024*512*2);
  u16*   Bf[2]; Bf[0]=(u16*)alloc(1024*256*2); Bf[1]=(u16*)alloc(1024*256*2);
  float* bp[2]; bp[0]=(float*)alloc(4096);     bp[1]=(float*)alloc(4096);
  u16*   Bs[2]; Bs[0]=(u16*)alloc(256*512*2);  Bs[1]=(u16*)alloc(256*512*2);
  float* csum = (float*)alloc(1024);
  float* csq  = (float*)alloc(1024);
  float* bns  = (float*)alloc(1024);
  float* bnt  = (float*)alloc(1024);
  u16*   W1f  = (u16*)  alloc(256*256*2);
  float* b1f  = (float*)alloc(1024);
  u16*   hA   = (u16*)  alloc((size_t)NREV*256*2);
  u16*   hB   = (u16*)  alloc((size_t)NREV*256*2);
  float* cT   = (float*)alloc((size_t)NREV*256*4);     // [unit j][row r], f32
  u16*   xW   = (u16*)  alloc((size_t)NUSER*1024*2);   // 134 MB, shared sequentially
  if(off > ws_size) return;  // insufficient workspace — fail cleanly
  u16* hln = hA;   // safe reuse after both SAGE GEMMs consumed h
  u16* z1  = hB;

  cvt_kernel<<<dim3(4096),256,0,stream>>>(x_review, xr, NREV*256/4);
  for(int rel=0; rel<2; ++rel){
    pack_lstm_kernel<<<dim3(1024),256,0,stream>>>(Wih[rel],Whh[rel],bih[rel],bhh[rel],Bp[rel],Bf[rel],bp[rel]);
    pack_sage_kernel<<<dim3(256), 256,0,stream>>>(Wself[rel],Wneigh[rel],Bs[rel]);
  }
  hipMemsetAsync(csum, 0, 1024, stream);
  hipMemsetAsync(csq,  0, 1024, stream);

  for(int rel=0; rel<2; ++rel){
    const float* xs = rel ? x_product : x_user;
    const int*   nb = rel ? nbr_prod  : nbr_user;
    xw_kernel<<<dim3(4096),256,0,stream>>>(xs, Bp[rel], bp[rel], xW);
    // recurrence: t==0 treats h,c as zero (no memsets needed)
    u16 *hin = hB, *hout = hA;
    for(int t=0; t<KNBR; ++t){
      lstm_step13_kernel<<<dim3(1024),256,0,stream>>>(xW, nb, t, Bf[rel], hin, hout, cT);
      u16* tmp = hin; hin = hout; hout = tmp;
    }
    // final h in hin (16 swaps, even). SAGE: A=[x_review | h_final], + bias, GELU, sum into hsum
    if(rel == 0)
      gemm_act_kernel<0><<<dim3(128,2),256,0,stream>>>(xr, hin, Bs[0], bconv[0], hsum, nullptr);
    else
      gemm_act_kernel<1><<<dim3(128,2),256,0,stream>>>(xr, hin, Bs[1], bconv[1], hsum, nullptr);
  }

  ln_kernel<<<dim3(4096),256,0,stream>>>(hsum, ln_g, ln_b, hln);
  colstats_kernel<<<dim3(128),256,0,stream>>>(hln, csum, csq);
  bnstat_kernel<<<dim3(1),256,0,stream>>>(csum, csq, bn_g, bn_b, bns, bnt);
  w1fold_kernel<<<dim3(256),256,0,stream>>>(W1, b1, bns, bnt, W1f, b1f);
  gemm_act_kernel<2><<<dim3(128,2),256,0,stream>>>(hln, nullptr, W1f, b1f, nullptr, z1);
  head_kernel<<<dim3(4096),256,0,stream>>>(z1, W2, b2, out);
}

// Round 18
// 1158.587 us; speedup vs baseline: 1.1969x; 1.1969x over previous
//
#include <hip/hip_runtime.h>
#include <math.h>

#define NREV 16384
#define NUSER 65536
#define NPROD 65536
#define KNBR 16
#define LDK 72   // padded LDS stride (bf16 elems): rows 16B-aligned, cheap bank phases

typedef __attribute__((ext_vector_type(8))) short short8;   // 8 bf16 (4 VGPRs) — MFMA A/B frag
typedef __attribute__((ext_vector_type(4))) float f32x4;    // MFMA C/D frag
typedef unsigned short u16;

__device__ __forceinline__ u16 f2bf(float f){
  union { float f; unsigned u; } x; x.f = f;
  unsigned r = x.u + 0x7fffu + ((x.u >> 16) & 1u);  // RNE
  return (u16)(r >> 16);
}
__device__ __forceinline__ float bf2f(u16 u){
  union { unsigned u; float f; } x; x.u = ((unsigned)u) << 16;
  return x.f;
}
// fast transcendentals: v_exp_f32 (2^x) + v_rcp_f32 direct. Saturation at +-inf is exact.
__device__ __forceinline__ float fexp2(float x){ return __builtin_amdgcn_exp2f(x); }
__device__ __forceinline__ float frcp(float x){ return __builtin_amdgcn_rcpf(x); }
#define LOG2E 1.4426950408889634f
__device__ __forceinline__ float sigf(float x){ return frcp(1.f + fexp2(-LOG2E*x)); }
__device__ __forceinline__ float tanh_fast(float x){ return 1.f - 2.f*frcp(1.f + fexp2(2.f*LOG2E*x)); }
__device__ __forceinline__ float gelu_fast(float x){
  float u = 0.7978845608f*x*(1.f + 0.044715f*x*x);
  return 0.5f*x*(1.f + tanh_fast(u));
}

// ---------------- f32 -> bf16 bulk convert (x_review only) ----------------
__global__ void cvt_kernel(const float* __restrict__ src, u16* __restrict__ dst, int n4){
  int i = blockIdx.x*256 + threadIdx.x;
  if(i < n4){
    float4 v = reinterpret_cast<const float4*>(src)[i];
    ushort4 o; o.x=f2bf(v.x); o.y=f2bf(v.y); o.z=f2bf(v.z); o.w=f2bf(v.w);
    reinterpret_cast<ushort4*>(dst)[i] = o;
  }
}

// ---------------- pack LSTM weights: Bp[n][k], n = 4*j + gate, k = [Wih | Whh] ----------------
__global__ void pack_lstm_kernel(const float* __restrict__ Wihp, const float* __restrict__ Whhp,
                                 const float* __restrict__ bihp, const float* __restrict__ bhhp,
                                 u16* __restrict__ Bpp, float* __restrict__ bpp){
  int n = blockIdx.x;              // 0..1023
  int g = n & 3, j = n >> 2;       // gate order i,f,g,o
  int m = g*256 + j;               // row in original (4F,F) weight
  int k = threadIdx.x;             // 0..255
  Bpp[(size_t)n*512 + k]       = f2bf(Wihp[(size_t)m*256 + k]);
  Bpp[(size_t)n*512 + 256 + k] = f2bf(Whhp[(size_t)m*256 + k]);
  if(k == 0) bpp[n] = bihp[m] + bhhp[m];
}

// ---------------- pack SAGE weights: Bs[n][k], k = [Wself | Wneigh] ----------------
__global__ void pack_sage_kernel(const float* __restrict__ Wselfp, const float* __restrict__ Wneighp,
                                 u16* __restrict__ Bsp){
  int n = blockIdx.x;              // 0..255
  int k = threadIdx.x;
  Bsp[(size_t)n*512 + k]       = f2bf(Wselfp[(size_t)n*256 + k]);
  Bsp[(size_t)n*512 + 256 + k] = f2bf(Wneighp[(size_t)n*256 + k]);
}

// ---------------- xW precompute v3: LDS-staged GEMM + LDS-staged COALESCED epilogue ----------------
// xw[node][n] = x[node]·Wih_packed[n] + b[n]. 1D grid 4096, XCD-swizzled (8 nt-siblings of one rt
// on the SAME XCD -> x tile L2 reuse). Output tile routed through LDS so global stores are
// 256B-contiguous row segments (vs 32B scattered chunks).
__global__ __launch_bounds__(256, 4) void xw_kernel(
    const float* __restrict__ x, const u16* __restrict__ Bp,
    const float* __restrict__ bp, u16* __restrict__ xwout)
{
  union SMX {
    struct { u16 A[128*LDK]; u16 B[128*LDK]; } st;  // 36.9 KB staging
    u16 O[128*136];                                  // 34.8 KB output tile (pad 136: 2-way only)
  };
  __shared__ SMX sm;
  int tid = threadIdx.x;
  int p = blockIdx.x;
  int xcd = p & 7, g = p >> 3;
  int nt = g & 7;
  int rt = (g >> 3) * 8 + xcd;             // 0..511
  f32x4 acc[4][4];
  #pragma unroll
  for(int i=0;i<4;++i)
    #pragma unroll
    for(int j=0;j<4;++j) acc[i][j] = (f32x4){0.f,0.f,0.f,0.f};
  int lane = tid & 63, w = tid >> 6, wr = w >> 1, wc = w & 1;
  int ci = tid & 7, r0 = tid >> 3;
  int rrow = lane & 15, lhi = lane >> 4, kb = lhi * 8;

  for(int kt=0; kt<4; ++kt){
    __syncthreads();
    #pragma unroll
    for(int pp=0; pp<4; ++pp){
      int row = pp*32 + r0;
      const float* srcA = x + (size_t)(rt*128 + row)*256 + kt*64 + ci*8;
      float4 a0 = *(const float4*)srcA;
      float4 a1 = *(const float4*)(srcA + 4);
      short8 s;
      s[0]=f2bf(a0.x); s[1]=f2bf(a0.y); s[2]=f2bf(a0.z); s[3]=f2bf(a0.w);
      s[4]=f2bf(a1.x); s[5]=f2bf(a1.y); s[6]=f2bf(a1.z); s[7]=f2bf(a1.w);
      *(short8*)&sm.st.A[row*LDK + ci*8] = s;
      *(short8*)&sm.st.B[row*LDK + ci*8] =
        *(const short8*)(Bp + (size_t)(nt*128 + row)*512 + kt*64 + ci*8);
    }
    __syncthreads();
    #pragma unroll
    for(int kk=0; kk<2; ++kk){
      short8 af[4], bfv[4];
      #pragma unroll
      for(int ni=0;ni<4;++ni) af[ni]  = *(const short8*)&sm.st.B[(wc*64+ni*16+rrow)*LDK + kk*32 + kb];
      #pragma unroll
      for(int mi=0;mi<4;++mi) bfv[mi] = *(const short8*)&sm.st.A[(wr*64+mi*16+rrow)*LDK + kk*32 + kb];
      #pragma unroll
      for(int ni=0;ni<4;++ni)
        #pragma unroll
        for(int mi=0;mi<4;++mi)
          acc[ni][mi] = __builtin_amdgcn_mfma_f32_16x16x32_bf16(af[ni], bfv[mi], acc[ni][mi], 0, 0, 0);
    }
  }
  // epilogue: stage tile into LDS (row-local layout), then coalesced 256B row-segment writes
  __syncthreads();   // all MFMA LDS reads done before aliasing
  #pragma unroll
  for(int mi=0;mi<4;++mi){
    int rl = wr*64 + mi*16 + rrow;
    #pragma unroll
    for(int ni=0;ni<4;++ni){
      int nl = wc*64 + ni*16 + lhi*4;
      float4 bv = *(const float4*)&bp[nt*128 + nl];
      ushort4 o;
      o.x = f2bf(acc[ni][mi][0] + bv.x);
      o.y = f2bf(acc[ni][mi][1] + bv.y);
      o.z = f2bf(acc[ni][mi][2] + bv.z);
      o.w = f2bf(acc[ni][mi][3] + bv.w);
      *(ushort4*)&sm.O[rl*136 + nl] = o;
    }
  }
  __syncthreads();
  #pragma unroll
  for(int it=0; it<8; ++it){
    int rl = it*16 + (tid >> 4);
    int ch = tid & 15;
    *(short8*)(xwout + (size_t)(rt*128 + rl)*1024 + nt*128 + ch*8) =
      *(const short8*)&sm.O[rl*136 + ch*8];
  }
}

// ---------------- LSTM step v10 (r13 proven): 128r x 128n, 256 thr, (256,3), XCD swizzle ----------------
__global__ __launch_bounds__(256, 3) void lstm_step10_kernel(
    const u16* __restrict__ xw, const int* __restrict__ nbr, int t,
    const u16* __restrict__ Bh,   // Whh half of packed rows (stride 512)
    const u16* __restrict__ hin, u16* __restrict__ hout, float* __restrict__ cT)
{
  __shared__ u16 sA[128*LDK];
  __shared__ u16 sB[128*LDK];
  int tid = threadIdx.x;
  int p = blockIdx.x;
  int xcd = p & 7, g = p >> 3;
  int nt = g & 7;
  int rt = (g >> 3) * 8 + xcd;             // 0..127
  int lane = tid & 63, w = tid >> 6, wr = w >> 1, wc = w & 1;
  int ci = tid & 7, r0 = tid >> 3;
  int rrow = lane & 15, lhi = lane >> 4, kb = lhi * 8;

  // gather prefetch: 16 x 8B loads in flight across the whole GEMM
  int node[4];
  #pragma unroll
  for(int mi=0;mi<4;++mi)
    node[mi] = nbr[(size_t)(rt*128 + wr*64 + mi*16 + rrow)*KNBR + t];
  ushort4 xv[4][4];
  #pragma unroll
  for(int mi=0;mi<4;++mi)
    #pragma unroll
    for(int ni=0;ni<4;++ni){
      int n0 = nt*128 + wc*64 + ni*16 + lhi*4;
      xv[mi][ni] = *(const ushort4*)(xw + (size_t)node[mi]*1024 + n0);
    }

  f32x4 acc[4][4];   // [ni][mi]
  #pragma unroll
  for(int i=0;i<4;++i)
    #pragma unroll
    for(int j=0;j<4;++j) acc[i][j] = (f32x4){0.f,0.f,0.f,0.f};

  if(t > 0){
    for(int kt=0; kt<4; ++kt){
      __syncthreads();
      #pragma unroll
      for(int pp=0; pp<4; ++pp){
        int row = pp*32 + r0;
        *(short8*)&sA[row*LDK + ci*8] =
          *(const short8*)(hin + (size_t)(rt*128 + row)*256 + kt*64 + ci*8);
        *(short8*)&sB[row*LDK + ci*8] =
          *(const short8*)(Bh + (size_t)(nt*128 + row)*512 + kt*64 + ci*8);
      }
      __syncthreads();
      #pragma unroll
      for(int kk=0; kk<2; ++kk){
        short8 af[4], bfv[4];
        #pragma unroll
        for(int ni=0;ni<4;++ni) af[ni]  = *(const short8*)&sB[(wc*64+ni*16+rrow)*LDK + kk*32 + kb];
        #pragma unroll
        for(int mi=0;mi<4;++mi) bfv[mi] = *(const short8*)&sA[(wr*64+mi*16+rrow)*LDK + kk*32 + kb];
        #pragma unroll
        for(int ni=0;ni<4;++ni)
          #pragma unroll
          for(int mi=0;mi<4;++mi)
            acc[ni][mi] = __builtin_amdgcn_mfma_f32_16x16x32_bf16(af[ni], bfv[mi], acc[ni][mi], 0, 0, 0);
      }
    }
  }

  // c loads issued after GEMM, before the transcendental chain
  float cv[4][4];
  #pragma unroll
  for(int mi=0;mi<4;++mi)
    #pragma unroll
    for(int ni=0;ni<4;++ni){
      cv[mi][ni] = 0.f;
      if(t > 0){
        int j = nt*32 + wc*16 + ni*4 + lhi;
        cv[mi][ni] = cT[(size_t)j*NREV + rt*128 + wr*64 + mi*16 + rrow];
      }
    }

  // fused cell update: acc elem q <-> packed n = 4*j + gate q (i,f,g,o)
  #pragma unroll
  for(int mi=0;mi<4;++mi){
    int rg = rt*128 + wr*64 + mi*16 + rrow;
    #pragma unroll
    for(int ni=0;ni<4;++ni){
      int j = nt*32 + wc*16 + ni*4 + lhi;
      float ig = bf2f(xv[mi][ni].x) + acc[ni][mi][0];
      float fg = bf2f(xv[mi][ni].y) + acc[ni][mi][1];
      float gg = bf2f(xv[mi][ni].z) + acc[ni][mi][2];
      float og = bf2f(xv[mi][ni].w) + acc[ni][mi][3];
      float cn = sigf(fg)*cv[mi][ni] + sigf(ig)*tanh_fast(gg);
      cT[(size_t)j*NREV + rg] = cn;
      hout[(size_t)rg*256 + j] = f2bf(sigf(og)*tanh_fast(cn));
    }
  }
}

// ---------------- generic GEMM + bias + GELU: MODE 0 = write f32, 1 = add f32, 2 = write bf16 ----------------
template<int MODE>
__global__ __launch_bounds__(256) void gemm_act_kernel(
    const u16* __restrict__ A0, const u16* __restrict__ A1,
    const u16* __restrict__ Bp, const float* __restrict__ bias,
    float* __restrict__ outF, u16* __restrict__ outH)
{
  constexpr int KT   = (MODE == 2) ? 4 : 8;
  constexpr int KTOT = KT * 64;
  __shared__ u16 sA[128*LDK];
  __shared__ u16 sB[128*LDK];
  int tid = threadIdx.x;
  int rt = blockIdx.x, nt = blockIdx.y;
  f32x4 acc[4][4];
  #pragma unroll
  for(int i=0;i<4;++i)
    #pragma unroll
    for(int j=0;j<4;++j) acc[i][j] = (f32x4){0.f,0.f,0.f,0.f};
  int lane = tid & 63, w = tid >> 6, wr = w >> 1, wc = w & 1;
  int ci = tid & 7, r0 = tid >> 3;
  int rrow = lane & 15, kb = (lane >> 4) * 8;

  for(int kt=0; kt<KT; ++kt){
    __syncthreads();
    #pragma unroll
    for(int pp=0; pp<4; ++pp){
      int row = pp*32 + r0;
      const u16* srcA = (kt < 4)
        ? (A0 + ((size_t)(rt*128 + row))*256 + kt*64)
        : (A1 + ((size_t)(rt*128 + row))*256 + (kt-4)*64);
      *(short8*)&sA[row*LDK + ci*8] = *(const short8*)(srcA + ci*8);
      const u16* srcB = Bp + ((size_t)(nt*128 + row))*KTOT + kt*64;
      *(short8*)&sB[row*LDK + ci*8] = *(const short8*)(srcB + ci*8);
    }
    __syncthreads();
    #pragma unroll
    for(int kk=0; kk<2; ++kk){
      short8 af[4], bfv[4];
      #pragma unroll
      for(int mi=0;mi<4;++mi) af[mi] = *(const short8*)&sA[(wr*64+mi*16+rrow)*LDK + kk*32 + kb];
      #pragma unroll
      for(int ni=0;ni<4;++ni) bfv[ni] = *(const short8*)&sB[(wc*64+ni*16+rrow)*LDK + kk*32 + kb];
      #pragma unroll
      for(int mi=0;mi<4;++mi)
        #pragma unroll
        for(int ni=0;ni<4;++ni)
          acc[mi][ni] = __builtin_amdgcn_mfma_f32_16x16x32_bf16(af[mi], bfv[ni], acc[mi][ni], 0, 0, 0);
    }
  }
  #pragma unroll
  for(int mi=0;mi<4;++mi)
    #pragma unroll
    for(int ni=0;ni<4;++ni){
      int col  = nt*128 + wc*64 + ni*16 + rrow;
      int rowb = rt*128 + wr*64 + mi*16 + (lane>>4)*4;
      float bv = bias[col];
      #pragma unroll
      for(int q=0;q<4;++q){
        float x = acc[mi][ni][q] + bv;
        float gl = gelu_fast(x);
        size_t idx = (size_t)(rowb+q)*256 + col;
        if(MODE == 0)      outF[idx] = gl;
        else if(MODE == 1) outF[idx] += gl;
        else               outH[idx] = f2bf(gl);
      }
    }
}

// ---------------- LayerNorm rowwise (256 feats), write bf16 ----------------
__global__ void ln_kernel(const float* __restrict__ hs, const float* __restrict__ g,
                          const float* __restrict__ b, u16* __restrict__ hlnp){
  int w = threadIdx.x >> 6, lane = threadIdx.x & 63;
  int r = blockIdx.x*4 + w;
  const float* row = hs + (size_t)r*256;
  float4 v = *(const float4*)(row + lane*4);
  float s  = v.x+v.y+v.z+v.w;
  float ss = v.x*v.x + v.y*v.y + v.z*v.z + v.w*v.w;
  #pragma unroll
  for(int d=1; d<64; d<<=1){ s += __shfl_xor(s, d, 64); ss += __shfl_xor(ss, d, 64); }
  float mu  = s  * (1.f/256.f);
  float var = ss * (1.f/256.f) - mu*mu;
  float rs  = rsqrtf(var + 1e-5f);
  float4 gv = *(const float4*)(g + lane*4);
  float4 bv = *(const float4*)(b + lane*4);
  ushort4 o;
  o.x = f2bf((v.x-mu)*rs*gv.x + bv.x);
  o.y = f2bf((v.y-mu)*rs*gv.y + bv.y);
  o.z = f2bf((v.z-mu)*rs*gv.z + bv.z);
  o.w = f2bf((v.w-mu)*rs*gv.w + bv.w);
  *(ushort4*)(hlnp + (size_t)r*256 + lane*4) = o;
}

// ---------------- column stats for BatchNorm ----------------
__global__ void colstats_kernel(const u16* __restrict__ hlnp, float* __restrict__ cs, float* __restrict__ cq){
  int cix = threadIdx.x;
  size_t rb = (size_t)blockIdx.x * 128;
  float s=0.f, q=0.f;
  for(int rr=0; rr<128; ++rr){
    float v = bf2f(hlnp[(rb+rr)*256 + cix]);
    s += v; q += v*v;
  }
  atomicAdd(&cs[cix], s);
  atomicAdd(&cq[cix], q);
}

// ---------------- BN stats -> scale/shift ----------------
__global__ void bnstat_kernel(const float* __restrict__ cs, const float* __restrict__ cq,
                              const float* __restrict__ bng, const float* __restrict__ bnb,
                              float* __restrict__ bns, float* __restrict__ bnt){
  int cix = threadIdx.x;
  float bm = cs[cix] * (1.f/16384.f);
  float bv = cq[cix] * (1.f/16384.f) - bm*bm;
  float s  = bng[cix] * rsqrtf(bv + 1e-5f);
  bns[cix] = s;
  bnt[cix] = bnb[cix] - bm*s;
}

// ---------------- fold BN into W1/b1 (parallel: one block per output row) ----------------
__global__ void w1fold_kernel(const float* __restrict__ W1p, const float* __restrict__ b1p,
                              const float* __restrict__ bns, const float* __restrict__ bnt,
                              u16* __restrict__ W1fp, float* __restrict__ b1fp){
  __shared__ float red[4];
  int n = blockIdx.x, k = threadIdx.x;
  int lane = k & 63, w = k >> 6;
  float wv = W1p[(size_t)n*256 + k];
  W1fp[(size_t)n*256 + k] = f2bf(wv * bns[k]);
  float p = wv * bnt[k];
  #pragma unroll
  for(int d=1; d<64; d<<=1) p += __shfl_xor(p, d, 64);
  if(lane == 0) red[w] = p;
  __syncthreads();
  if(k == 0) b1fp[n] = b1p[n] + red[0] + red[1] + red[2] + red[3];
}

// ---------------- head ----------------
__global__ void head_kernel(const u16* __restrict__ z, const float* __restrict__ W2p,
                            const float* __restrict__ b2p, float* __restrict__ outp){
  int w = threadIdx.x >> 6, lane = threadIdx.x & 63;
  int r = blockIdx.x*4 + w;
  const u16* zr = z + (size_t)r*256;
  ushort4 v = *(const ushort4*)(zr + lane*4);
  float z0=bf2f(v.x), z1v=bf2f(v.y), z2=bf2f(v.z), z3=bf2f(v.w);
  float4 wa = *(const float4*)(W2p + lane*4);
  float4 wb = *(const float4*)(W2p + 256 + lane*4);
  float p0 = z0*wa.x + z1v*wa.y + z2*wa.z + z3*wa.w;
  float p1 = z0*wb.x + z1v*wb.y + z2*wb.z + z3*wb.w;
  #pragma unroll
  for(int d=1; d<64; d<<=1){ p0 += __shfl_xor(p0,d,64); p1 += __shfl_xor(p1,d,64); }
  if(lane == 0){
    outp[(size_t)r*2]   = p0 + b2p[0];
    outp[(size_t)r*2+1] = p1 + b2p[1];
  }
}

extern "C" void kernel_launch(void* const* d_in, const int* in_sizes, int n_in,
                              void* d_out, int out_size, void* d_ws, size_t ws_size,
                              hipStream_t stream){
  (void)in_sizes; (void)n_in; (void)out_size;
  const float* x_user    = (const float*)d_in[0];
  const float* x_product = (const float*)d_in[1];
  const float* x_review  = (const float*)d_in[2];
  const int*   nbr_user  = (const int*)d_in[3];
  const int*   nbr_prod  = (const int*)d_in[4];
  const float* Wih[2]    = {(const float*)d_in[5],  (const float*)d_in[12]};
  const float* Whh[2]    = {(const float*)d_in[6],  (const float*)d_in[13]};
  const float* bih[2]    = {(const float*)d_in[7],  (const float*)d_in[14]};
  const float* bhh[2]    = {(const float*)d_in[8],  (const float*)d_in[15]};
  const float* Wself[2]  = {(const float*)d_in[9],  (const float*)d_in[16]};
  const float* Wneigh[2] = {(const float*)d_in[10], (const float*)d_in[17]};
  const float* bconv[2]  = {(const float*)d_in[11], (const float*)d_in[18]};
  const float* ln_g=(const float*)d_in[19], *ln_b=(const float*)d_in[20];
  const float* bn_g=(const float*)d_in[21], *bn_b=(const float*)d_in[22];
  const float* W1=(const float*)d_in[23], *b1=(const float*)d_in[24];
  const float* W2=(const float*)d_in[25], *b2=(const float*)d_in[26];
  float* out = (float*)d_out;

  char* base = (char*)d_ws;
  size_t off = 0;
  auto alloc = [&](size_t bytes)->char* { char* r = base + off; off += (bytes + 255) & ~(size_t)255; return r; };
  u16*   xr   = (u16*)  alloc((size_t)NREV*256*2);
  float* hsum = (float*)alloc((size_t)NREV*256*4);
  u16*   Bp[2]; Bp[0]=(u16*)alloc(1024*512*2); Bp[1]=(u16*)alloc(1024*512*2);
  float* bp[2]; bp[0]=(float*)alloc(4096);     bp[1]=(float*)alloc(4096);
  u16*   Bs[2]; Bs[0]=(u16*)alloc(256*512*2);  Bs[1]=(u16*)alloc(256*512*2);
  float* csum = (float*)alloc(1024);
  float* csq  = (float*)alloc(1024);
  float* bns  = (float*)alloc(1024);
  float* bnt  = (float*)alloc(1024);
  u16*   W1f  = (u16*)  alloc(256*256*2);
  float* b1f  = (float*)alloc(1024);
  u16*   hA   = (u16*)  alloc((size_t)NREV*256*2);
  u16*   hB   = (u16*)  alloc((size_t)NREV*256*2);
  float* cT   = (float*)alloc((size_t)NREV*256*4);     // [unit j][row r], f32
  u16*   xW   = (u16*)  alloc((size_t)NUSER*1024*2);   // 134 MB, shared sequentially
  if(off > ws_size) return;  // insufficient workspace — fail cleanly
  u16* hln = hA;   // safe reuse after both SAGE GEMMs consumed h
  u16* z1  = hB;

  cvt_kernel<<<dim3(4096),256,0,stream>>>(x_review, xr, NREV*256/4);
  for(int rel=0; rel<2; ++rel){
    pack_lstm_kernel<<<dim3(1024),256,0,stream>>>(Wih[rel],Whh[rel],bih[rel],bhh[rel],Bp[rel],bp[rel]);
    pack_sage_kernel<<<dim3(256), 256,0,stream>>>(Wself[rel],Wneigh[rel],Bs[rel]);
  }
  hipMemsetAsync(csum, 0, 1024, stream);
  hipMemsetAsync(csq,  0, 1024, stream);

  for(int rel=0; rel<2; ++rel){
    const float* xs = rel ? x_product : x_user;
    const int*   nb = rel ? nbr_prod  : nbr_user;
    xw_kernel<<<dim3(4096),256,0,stream>>>(xs, Bp[rel], bp[rel], xW);
    // recurrence: t==0 treats h,c as zero (no memsets needed)
    u16 *hin = hB, *hout = hA;
    for(int t=0; t<KNBR; ++t){
      lstm_step10_kernel<<<dim3(1024),256,0,stream>>>(xW, nb, t, Bp[rel] + 256, hin, hout, cT);
      u16* tmp = hin; hin = hout; hout = tmp;
    }
    // final h in hin (16 swaps, even). SAGE: A=[x_review | h_final], + bias, GELU, sum into hsum
    if(rel == 0)
      gemm_act_kernel<0><<<dim3(128,2),256,0,stream>>>(xr, hin, Bs[0], bconv[0], hsum, nullptr);
    else
      gemm_act_kernel<1><<<dim3(128,2),256,0,stream>>>(xr, hin, Bs[1], bconv[1], hsum, nullptr);
  }

  ln_kernel<<<dim3(4096),256,0,stream>>>(hsum, ln_g, ln_b, hln);
  colstats_kernel<<<dim3(128),256,0,stream>>>(hln, csum, csq);
  bnstat_kernel<<<dim3(1),256,0,stream>>>(csum, csq, bn_g, bn_b, bns, bnt);
  w1fold_kernel<<<dim3(256),256,0,stream>>>(W1, b1, bns, bnt, W1f, b1f);
  gemm_act_kernel<2><<<dim3(128,2),256,0,stream>>>(hln, nullptr, W1f, b1f, nullptr, z1);
  head_kernel<<<dim3(4096),256,0,stream>>>(z1, W2, b2, out);
}

// Round 19
// 1151.397 us; speedup vs baseline: 1.2044x; 1.0062x over previous
//
#include <hip/hip_runtime.h>
#include <math.h>

#define NREV 16384
#define NUSER 65536
#define NPROD 65536
#define KNBR 16
#define LDK 72   // padded LDS stride (bf16 elems): rows 16B-aligned, cheap bank phases

typedef __attribute__((ext_vector_type(8))) short short8;   // 8 bf16 (4 VGPRs) — MFMA A/B frag
typedef __attribute__((ext_vector_type(4))) float f32x4;    // MFMA C/D frag
typedef unsigned short u16;

__device__ __forceinline__ u16 f2bf(float f){
  union { float f; unsigned u; } x; x.f = f;
  unsigned r = x.u + 0x7fffu + ((x.u >> 16) & 1u);  // RNE
  return (u16)(r >> 16);
}
__device__ __forceinline__ float bf2f(u16 u){
  union { unsigned u; float f; } x; x.u = ((unsigned)u) << 16;
  return x.f;
}
// fast transcendentals: v_exp_f32 (2^x) + v_rcp_f32 direct. Saturation at +-inf is exact.
__device__ __forceinline__ float fexp2(float x){ return __builtin_amdgcn_exp2f(x); }
__device__ __forceinline__ float frcp(float x){ return __builtin_amdgcn_rcpf(x); }
#define LOG2E 1.4426950408889634f
__device__ __forceinline__ float sigf(float x){ return frcp(1.f + fexp2(-LOG2E*x)); }
__device__ __forceinline__ float tanh_fast(float x){ return 1.f - 2.f*frcp(1.f + fexp2(2.f*LOG2E*x)); }
__device__ __forceinline__ float gelu_fast(float x){
  float u = 0.7978845608f*x*(1.f + 0.044715f*x*x);
  return 0.5f*x*(1.f + tanh_fast(u));
}

// ---------------- f32 -> bf16 bulk convert (x_review only) ----------------
__global__ void cvt_kernel(const float* __restrict__ src, u16* __restrict__ dst, int n4){
  int i = blockIdx.x*256 + threadIdx.x;
  if(i < n4){
    float4 v = reinterpret_cast<const float4*>(src)[i];
    ushort4 o; o.x=f2bf(v.x); o.y=f2bf(v.y); o.z=f2bf(v.z); o.w=f2bf(v.w);
    reinterpret_cast<ushort4*>(dst)[i] = o;
  }
}

// ---------------- pack LSTM weights: Bp[n][k], n = 4*j + gate, k = [Wih | Whh] ----------------
__global__ void pack_lstm_kernel(const float* __restrict__ Wihp, const float* __restrict__ Whhp,
                                 const float* __restrict__ bihp, const float* __restrict__ bhhp,
                                 u16* __restrict__ Bpp, float* __restrict__ bpp){
  int n = blockIdx.x;              // 0..1023
  int g = n & 3, j = n >> 2;       // gate order i,f,g,o
  int m = g*256 + j;               // row in original (4F,F) weight
  int k = threadIdx.x;             // 0..255
  Bpp[(size_t)n*512 + k]       = f2bf(Wihp[(size_t)m*256 + k]);
  Bpp[(size_t)n*512 + 256 + k] = f2bf(Whhp[(size_t)m*256 + k]);
  if(k == 0) bpp[n] = bihp[m] + bhhp[m];
}

// ---------------- pack SAGE weights: Bs[n][k], k = [Wself | Wneigh] ----------------
__global__ void pack_sage_kernel(const float* __restrict__ Wselfp, const float* __restrict__ Wneighp,
                                 u16* __restrict__ Bsp){
  int n = blockIdx.x;              // 0..255
  int k = threadIdx.x;
  Bsp[(size_t)n*512 + k]       = f2bf(Wselfp[(size_t)n*256 + k]);
  Bsp[(size_t)n*512 + 256 + k] = f2bf(Wneighp[(size_t)n*256 + k]);
}

// ---------------- xW precompute v3 (r16 proven): LDS GEMM + coalesced LDS epilogue ----------------
__global__ __launch_bounds__(256, 4) void xw_kernel(
    const float* __restrict__ x, const u16* __restrict__ Bp,
    const float* __restrict__ bp, u16* __restrict__ xwout)
{
  union SMX {
    struct { u16 A[128*LDK]; u16 B[128*LDK]; } st;  // 36.9 KB staging
    u16 O[128*136];                                  // 34.8 KB output tile (pad 136: 2-way only)
  };
  __shared__ SMX sm;
  int tid = threadIdx.x;
  int p = blockIdx.x;
  int xcd = p & 7, g = p >> 3;
  int nt = g & 7;
  int rt = (g >> 3) * 8 + xcd;             // 0..511
  f32x4 acc[4][4];
  #pragma unroll
  for(int i=0;i<4;++i)
    #pragma unroll
    for(int j=0;j<4;++j) acc[i][j] = (f32x4){0.f,0.f,0.f,0.f};
  int lane = tid & 63, w = tid >> 6, wr = w >> 1, wc = w & 1;
  int ci = tid & 7, r0 = tid >> 3;
  int rrow = lane & 15, lhi = lane >> 4, kb = lhi * 8;

  for(int kt=0; kt<4; ++kt){
    __syncthreads();
    #pragma unroll
    for(int pp=0; pp<4; ++pp){
      int row = pp*32 + r0;
      const float* srcA = x + (size_t)(rt*128 + row)*256 + kt*64 + ci*8;
      float4 a0 = *(const float4*)srcA;
      float4 a1 = *(const float4*)(srcA + 4);
      short8 s;
      s[0]=f2bf(a0.x); s[1]=f2bf(a0.y); s[2]=f2bf(a0.z); s[3]=f2bf(a0.w);
      s[4]=f2bf(a1.x); s[5]=f2bf(a1.y); s[6]=f2bf(a1.z); s[7]=f2bf(a1.w);
      *(short8*)&sm.st.A[row*LDK + ci*8] = s;
      *(short8*)&sm.st.B[row*LDK + ci*8] =
        *(const short8*)(Bp + (size_t)(nt*128 + row)*512 + kt*64 + ci*8);
    }
    __syncthreads();
    #pragma unroll
    for(int kk=0; kk<2; ++kk){
      short8 af[4], bfv[4];
      #pragma unroll
      for(int ni=0;ni<4;++ni) af[ni]  = *(const short8*)&sm.st.B[(wc*64+ni*16+rrow)*LDK + kk*32 + kb];
      #pragma unroll
      for(int mi=0;mi<4;++mi) bfv[mi] = *(const short8*)&sm.st.A[(wr*64+mi*16+rrow)*LDK + kk*32 + kb];
      #pragma unroll
      for(int ni=0;ni<4;++ni)
        #pragma unroll
        for(int mi=0;mi<4;++mi)
          acc[ni][mi] = __builtin_amdgcn_mfma_f32_16x16x32_bf16(af[ni], bfv[mi], acc[ni][mi], 0, 0, 0);
    }
  }
  // epilogue: stage tile into LDS (row-local layout), then coalesced 256B row-segment writes
  __syncthreads();   // all MFMA LDS reads done before aliasing
  #pragma unroll
  for(int mi=0;mi<4;++mi){
    int rl = wr*64 + mi*16 + rrow;
    #pragma unroll
    for(int ni=0;ni<4;++ni){
      int nl = wc*64 + ni*16 + lhi*4;
      float4 bv = *(const float4*)&bp[nt*128 + nl];
      ushort4 o;
      o.x = f2bf(acc[ni][mi][0] + bv.x);
      o.y = f2bf(acc[ni][mi][1] + bv.y);
      o.z = f2bf(acc[ni][mi][2] + bv.z);
      o.w = f2bf(acc[ni][mi][3] + bv.w);
      *(ushort4*)&sm.O[rl*136 + nl] = o;
    }
  }
  __syncthreads();
  #pragma unroll
  for(int it=0; it<8; ++it){
    int rl = it*16 + (tid >> 4);
    int ch = tid & 15;
    *(short8*)(xwout + (size_t)(rt*128 + rl)*1024 + nt*128 + ch*8) =
      *(const short8*)&sm.O[rl*136 + ch*8];
  }
}

// ---------------- LSTM step v10 (r13 proven): 128r x 128n, 256 thr, (256,3), XCD swizzle ----------------
__global__ __launch_bounds__(256, 3) void lstm_step10_kernel(
    const u16* __restrict__ xw, const int* __restrict__ nbr, int t,
    const u16* __restrict__ Bh,   // Whh half of packed rows (stride 512)
    const u16* __restrict__ hin, u16* __restrict__ hout, float* __restrict__ cT)
{
  __shared__ u16 sA[128*LDK];
  __shared__ u16 sB[128*LDK];
  int tid = threadIdx.x;
  int p = blockIdx.x;
  int xcd = p & 7, g = p >> 3;
  int nt = g & 7;
  int rt = (g >> 3) * 8 + xcd;             // 0..127
  int lane = tid & 63, w = tid >> 6, wr = w >> 1, wc = w & 1;
  int ci = tid & 7, r0 = tid >> 3;
  int rrow = lane & 15, lhi = lane >> 4, kb = lhi * 8;

  // gather prefetch: 16 x 8B loads in flight across the whole GEMM
  int node[4];
  #pragma unroll
  for(int mi=0;mi<4;++mi)
    node[mi] = nbr[(size_t)(rt*128 + wr*64 + mi*16 + rrow)*KNBR + t];
  ushort4 xv[4][4];
  #pragma unroll
  for(int mi=0;mi<4;++mi)
    #pragma unroll
    for(int ni=0;ni<4;++ni){
      int n0 = nt*128 + wc*64 + ni*16 + lhi*4;
      xv[mi][ni] = *(const ushort4*)(xw + (size_t)node[mi]*1024 + n0);
    }

  f32x4 acc[4][4];   // [ni][mi]
  #pragma unroll
  for(int i=0;i<4;++i)
    #pragma unroll
    for(int j=0;j<4;++j) acc[i][j] = (f32x4){0.f,0.f,0.f,0.f};

  if(t > 0){
    for(int kt=0; kt<4; ++kt){
      __syncthreads();
      #pragma unroll
      for(int pp=0; pp<4; ++pp){
        int row = pp*32 + r0;
        *(short8*)&sA[row*LDK + ci*8] =
          *(const short8*)(hin + (size_t)(rt*128 + row)*256 + kt*64 + ci*8);
        *(short8*)&sB[row*LDK + ci*8] =
          *(const short8*)(Bh + (size_t)(nt*128 + row)*512 + kt*64 + ci*8);
      }
      __syncthreads();
      #pragma unroll
      for(int kk=0; kk<2; ++kk){
        short8 af[4], bfv[4];
        #pragma unroll
        for(int ni=0;ni<4;++ni) af[ni]  = *(const short8*)&sB[(wc*64+ni*16+rrow)*LDK + kk*32 + kb];
        #pragma unroll
        for(int mi=0;mi<4;++mi) bfv[mi] = *(const short8*)&sA[(wr*64+mi*16+rrow)*LDK + kk*32 + kb];
        #pragma unroll
        for(int ni=0;ni<4;++ni)
          #pragma unroll
          for(int mi=0;mi<4;++mi)
            acc[ni][mi] = __builtin_amdgcn_mfma_f32_16x16x32_bf16(af[ni], bfv[mi], acc[ni][mi], 0, 0, 0);
      }
    }
  }

  // c loads issued after GEMM, before the transcendental chain
  float cv[4][4];
  #pragma unroll
  for(int mi=0;mi<4;++mi)
    #pragma unroll
    for(int ni=0;ni<4;++ni){
      cv[mi][ni] = 0.f;
      if(t > 0){
        int j = nt*32 + wc*16 + ni*4 + lhi;
        cv[mi][ni] = cT[(size_t)j*NREV + rt*128 + wr*64 + mi*16 + rrow];
      }
    }

  // fused cell update: acc elem q <-> packed n = 4*j + gate q (i,f,g,o)
  #pragma unroll
  for(int mi=0;mi<4;++mi){
    int rg = rt*128 + wr*64 + mi*16 + rrow;
    #pragma unroll
    for(int ni=0;ni<4;++ni){
      int j = nt*32 + wc*16 + ni*4 + lhi;
      float ig = bf2f(xv[mi][ni].x) + acc[ni][mi][0];
      float fg = bf2f(xv[mi][ni].y) + acc[ni][mi][1];
      float gg = bf2f(xv[mi][ni].z) + acc[ni][mi][2];
      float og = bf2f(xv[mi][ni].w) + acc[ni][mi][3];
      float cn = sigf(fg)*cv[mi][ni] + sigf(ig)*tanh_fast(gg);
      cT[(size_t)j*NREV + rg] = cn;
      hout[(size_t)rg*256 + j] = f2bf(sigf(og)*tanh_fast(cn));
    }
  }
}

// ---------------- generic GEMM + bias + GELU v2: 64-row tiles, XCD swizzle, 2 blocks/CU ----------------
// MODE 0 = write f32, 1 = add f32, 2 = write bf16. 1D grid 512: xcd=p&7, g=p>>3, nt=g&1,
// rt=(g>>1)*8+xcd (0..255, 64-row tiles). Wave-tile 32r x 64c (acc 2x4 = 32 VGPR).
template<int MODE>
__global__ __launch_bounds__(256, 3) void gemm_act_kernel(
    const u16* __restrict__ A0, const u16* __restrict__ A1,
    const u16* __restrict__ Bp, const float* __restrict__ bias,
    float* __restrict__ outF, u16* __restrict__ outH)
{
  constexpr int KT   = (MODE == 2) ? 4 : 8;
  constexpr int KTOT = KT * 64;
  __shared__ u16 sA[64*LDK];
  __shared__ u16 sB[128*LDK];
  int tid = threadIdx.x;
  int p = blockIdx.x;
  int xcd = p & 7, g = p >> 3;
  int nt = g & 1;
  int rt = (g >> 1) * 8 + xcd;     // 0..255
  f32x4 acc[2][4];                 // [mi][ni]
  #pragma unroll
  for(int i=0;i<2;++i)
    #pragma unroll
    for(int j=0;j<4;++j) acc[i][j] = (f32x4){0.f,0.f,0.f,0.f};
  int lane = tid & 63, w = tid >> 6, wr = w >> 1, wc = w & 1;
  int ci = tid & 7, r0 = tid >> 3;          // r0 in [0,32)
  int rrow = lane & 15, lhi = lane >> 4, kb = lhi * 8;

  for(int kt=0; kt<KT; ++kt){
    __syncthreads();
    #pragma unroll
    for(int pp=0; pp<2; ++pp){
      int row = pp*32 + r0;
      const u16* srcA = (kt < 4)
        ? (A0 + ((size_t)(rt*64 + row))*256 + kt*64)
        : (A1 + ((size_t)(rt*64 + row))*256 + (kt-4)*64);
      *(short8*)&sA[row*LDK + ci*8] = *(const short8*)(srcA + ci*8);
    }
    #pragma unroll
    for(int pp=0; pp<4; ++pp){
      int row = pp*32 + r0;
      *(short8*)&sB[row*LDK + ci*8] =
        *(const short8*)(Bp + ((size_t)(nt*128 + row))*KTOT + kt*64 + ci*8);
    }
    __syncthreads();
    #pragma unroll
    for(int kk=0; kk<2; ++kk){
      short8 af[2], bfv[4];
      #pragma unroll
      for(int mi=0;mi<2;++mi) af[mi] = *(const short8*)&sA[(wr*32+mi*16+rrow)*LDK + kk*32 + kb];
      #pragma unroll
      for(int ni=0;ni<4;++ni) bfv[ni] = *(const short8*)&sB[(wc*64+ni*16+rrow)*LDK + kk*32 + kb];
      #pragma unroll
      for(int mi=0;mi<2;++mi)
        #pragma unroll
        for(int ni=0;ni<4;++ni)
          acc[mi][ni] = __builtin_amdgcn_mfma_f32_16x16x32_bf16(af[mi], bfv[ni], acc[mi][ni], 0, 0, 0);
    }
  }
  #pragma unroll
  for(int mi=0;mi<2;++mi)
    #pragma unroll
    for(int ni=0;ni<4;++ni){
      int col  = nt*128 + wc*64 + ni*16 + rrow;
      int rowb = rt*64 + wr*32 + mi*16 + lhi*4;
      float bv = bias[col];
      #pragma unroll
      for(int q=0;q<4;++q){
        float x = acc[mi][ni][q] + bv;
        float gl = gelu_fast(x);
        size_t idx = (size_t)(rowb+q)*256 + col;
        if(MODE == 0)      outF[idx] = gl;
        else if(MODE == 1) outF[idx] += gl;
        else               outH[idx] = f2bf(gl);
      }
    }
}

// ---------------- LayerNorm rowwise (256 feats), write bf16 ----------------
__global__ void ln_kernel(const float* __restrict__ hs, const float* __restrict__ g,
                          const float* __restrict__ b, u16* __restrict__ hlnp){
  int w = threadIdx.x >> 6, lane = threadIdx.x & 63;
  int r = blockIdx.x*4 + w;
  const float* row = hs + (size_t)r*256;
  float4 v = *(const float4*)(row + lane*4);
  float s  = v.x+v.y+v.z+v.w;
  float ss = v.x*v.x + v.y*v.y + v.z*v.z + v.w*v.w;
  #pragma unroll
  for(int d=1; d<64; d<<=1){ s += __shfl_xor(s, d, 64); ss += __shfl_xor(ss, d, 64); }
  float mu  = s  * (1.f/256.f);
  float var = ss * (1.f/256.f) - mu*mu;
  float rs  = rsqrtf(var + 1e-5f);
  float4 gv = *(const float4*)(g + lane*4);
  float4 bv = *(const float4*)(b + lane*4);
  ushort4 o;
  o.x = f2bf((v.x-mu)*rs*gv.x + bv.x);
  o.y = f2bf((v.y-mu)*rs*gv.y + bv.y);
  o.z = f2bf((v.z-mu)*rs*gv.z + bv.z);
  o.w = f2bf((v.w-mu)*rs*gv.w + bv.w);
  *(ushort4*)(hlnp + (size_t)r*256 + lane*4) = o;
}

// ---------------- column stats for BatchNorm ----------------
__global__ void colstats_kernel(const u16* __restrict__ hlnp, float* __restrict__ cs, float* __restrict__ cq){
  int cix = threadIdx.x;
  size_t rb = (size_t)blockIdx.x * 128;
  float s=0.f, q=0.f;
  for(int rr=0; rr<128; ++rr){
    float v = bf2f(hlnp[(rb+rr)*256 + cix]);
    s += v; q += v*v;
  }
  atomicAdd(&cs[cix], s);
  atomicAdd(&cq[cix], q);
}

// ---------------- BN stats -> scale/shift ----------------
__global__ void bnstat_kernel(const float* __restrict__ cs, const float* __restrict__ cq,
                              const float* __restrict__ bng, const float* __restrict__ bnb,
                              float* __restrict__ bns, float* __restrict__ bnt){
  int cix = threadIdx.x;
  float bm = cs[cix] * (1.f/16384.f);
  float bv = cq[cix] * (1.f/16384.f) - bm*bm;
  float s  = bng[cix] * rsqrtf(bv + 1e-5f);
  bns[cix] = s;
  bnt[cix] = bnb[cix] - bm*s;
}

// ---------------- fold BN into W1/b1 (parallel: one block per output row) ----------------
__global__ void w1fold_kernel(const float* __restrict__ W1p, const float* __restrict__ b1p,
                              const float* __restrict__ bns, const float* __restrict__ bnt,
                              u16* __restrict__ W1fp, float* __restrict__ b1fp){
  __shared__ float red[4];
  int n = blockIdx.x, k = threadIdx.x;
  int lane = k & 63, w = k >> 6;
  float wv = W1p[(size_t)n*256 + k];
  W1fp[(size_t)n*256 + k] = f2bf(wv * bns[k]);
  float p = wv * bnt[k];
  #pragma unroll
  for(int d=1; d<64; d<<=1) p += __shfl_xor(p, d, 64);
  if(lane == 0) red[w] = p;
  __syncthreads();
  if(k == 0) b1fp[n] = b1p[n] + red[0] + red[1] + red[2] + red[3];
}

// ---------------- head ----------------
__global__ void head_kernel(const u16* __restrict__ z, const float* __restrict__ W2p,
                            const float* __restrict__ b2p, float* __restrict__ outp){
  int w = threadIdx.x >> 6, lane = threadIdx.x & 63;
  int r = blockIdx.x*4 + w;
  const u16* zr = z + (size_t)r*256;
  ushort4 v = *(const ushort4*)(zr + lane*4);
  float z0=bf2f(v.x), z1v=bf2f(v.y), z2=bf2f(v.z), z3=bf2f(v.w);
  float4 wa = *(const float4*)(W2p + lane*4);
  float4 wb = *(const float4*)(W2p + 256 + lane*4);
  float p0 = z0*wa.x + z1v*wa.y + z2*wa.z + z3*wa.w;
  float p1 = z0*wb.x + z1v*wb.y + z2*wb.z + z3*wb.w;
  #pragma unroll
  for(int d=1; d<64; d<<=1){ p0 += __shfl_xor(p0,d,64); p1 += __shfl_xor(p1,d,64); }
  if(lane == 0){
    outp[(size_t)r*2]   = p0 + b2p[0];
    outp[(size_t)r*2+1] = p1 + b2p[1];
  }
}

extern "C" void kernel_launch(void* const* d_in, const int* in_sizes, int n_in,
                              void* d_out, int out_size, void* d_ws, size_t ws_size,
                              hipStream_t stream){
  (void)in_sizes; (void)n_in; (void)out_size;
  const float* x_user    = (const float*)d_in[0];
  const float* x_product = (const float*)d_in[1];
  const float* x_review  = (const float*)d_in[2];
  const int*   nbr_user  = (const int*)d_in[3];
  const int*   nbr_prod  = (const int*)d_in[4];
  const float* Wih[2]    = {(const float*)d_in[5],  (const float*)d_in[12]};
  const float* Whh[2]    = {(const float*)d_in[6],  (const float*)d_in[13]};
  const float* bih[2]    = {(const float*)d_in[7],  (const float*)d_in[14]};
  const float* bhh[2]    = {(const float*)d_in[8],  (const float*)d_in[15]};
  const float* Wself[2]  = {(const float*)d_in[9],  (const float*)d_in[16]};
  const float* Wneigh[2] = {(const float*)d_in[10], (const float*)d_in[17]};
  const float* bconv[2]  = {(const float*)d_in[11], (const float*)d_in[18]};
  const float* ln_g=(const float*)d_in[19], *ln_b=(const float*)d_in[20];
  const float* bn_g=(const float*)d_in[21], *bn_b=(const float*)d_in[22];
  const float* W1=(const float*)d_in[23], *b1=(const float*)d_in[24];
  const float* W2=(const float*)d_in[25], *b2=(const float*)d_in[26];
  float* out = (float*)d_out;

  char* base = (char*)d_ws;
  size_t off = 0;
  auto alloc = [&](size_t bytes)->char* { char* r = base + off; off += (bytes + 255) & ~(size_t)255; return r; };
  u16*   xr   = (u16*)  alloc((size_t)NREV*256*2);
  float* hsum = (float*)alloc((size_t)NREV*256*4);
  u16*   Bp[2]; Bp[0]=(u16*)alloc(1024*512*2); Bp[1]=(u16*)alloc(1024*512*2);
  float* bp[2]; bp[0]=(float*)alloc(4096);     bp[1]=(float*)alloc(4096);
  u16*   Bs[2]; Bs[0]=(u16*)alloc(256*512*2);  Bs[1]=(u16*)alloc(256*512*2);
  float* csum = (float*)alloc(1024);
  float* csq  = (float*)alloc(1024);
  float* bns  = (float*)alloc(1024);
  float* bnt  = (float*)alloc(1024);
  u16*   W1f  = (u16*)  alloc(256*256*2);
  float* b1f  = (float*)alloc(1024);
  u16*   hA   = (u16*)  alloc((size_t)NREV*256*2);
  u16*   hB   = (u16*)  alloc((size_t)NREV*256*2);
  float* cT   = (float*)alloc((size_t)NREV*256*4);     // [unit j][row r], f32
  u16*   xW   = (u16*)  alloc((size_t)NUSER*1024*2);   // 134 MB, shared sequentially
  if(off > ws_size) return;  // insufficient workspace — fail cleanly
  u16* hln = hA;   // safe reuse after both SAGE GEMMs consumed h
  u16* z1  = hB;

  cvt_kernel<<<dim3(4096),256,0,stream>>>(x_review, xr, NREV*256/4);
  for(int rel=0; rel<2; ++rel){
    pack_lstm_kernel<<<dim3(1024),256,0,stream>>>(Wih[rel],Whh[rel],bih[rel],bhh[rel],Bp[rel],bp[rel]);
    pack_sage_kernel<<<dim3(256), 256,0,stream>>>(Wself[rel],Wneigh[rel],Bs[rel]);
  }
  hipMemsetAsync(csum, 0, 1024, stream);
  hipMemsetAsync(csq,  0, 1024, stream);

  for(int rel=0; rel<2; ++rel){
    const float* xs = rel ? x_product : x_user;
    const int*   nb = rel ? nbr_prod  : nbr_user;
    xw_kernel<<<dim3(4096),256,0,stream>>>(xs, Bp[rel], bp[rel], xW);
    // recurrence: t==0 treats h,c as zero (no memsets needed)
    u16 *hin = hB, *hout = hA;
    for(int t=0; t<KNBR; ++t){
      lstm_step10_kernel<<<dim3(1024),256,0,stream>>>(xW, nb, t, Bp[rel] + 256, hin, hout, cT);
      u16* tmp = hin; hin = hout; hout = tmp;
    }
    // final h in hin (16 swaps, even). SAGE: A=[x_review | h_final], + bias, GELU, sum into hsum
    if(rel == 0)
      gemm_act_kernel<0><<<dim3(512),256,0,stream>>>(xr, hin, Bs[0], bconv[0], hsum, nullptr);
    else
      gemm_act_kernel<1><<<dim3(512),256,0,stream>>>(xr, hin, Bs[1], bconv[1], hsum, nullptr);
  }

  ln_kernel<<<dim3(4096),256,0,stream>>>(hsum, ln_g, ln_b, hln);
  colstats_kernel<<<dim3(128),256,0,stream>>>(hln, csum, csq);
  bnstat_kernel<<<dim3(1),256,0,stream>>>(csum, csq, bn_g, bn_b, bns, bnt);
  w1fold_kernel<<<dim3(256),256,0,stream>>>(W1, b1, bns, bnt, W1f, b1f);
  gemm_act_kernel<2><<<dim3(512),256,0,stream>>>(hln, nullptr, W1f, b1f, nullptr, z1);
  head_kernel<<<dim3(4096),256,0,stream>>>(z1, W2, b2, out);
}